// Round 1
// baseline (503.444 us; speedup 1.0000x reference)
//
#include <hip/hip_runtime.h>
#include <math.h>

#define HS 4096
#define NIN 17
#define ROW_CHUNKS 128
#define ROWS_PER_CHUNK (HS / ROW_CHUNKS)   // 32

// Partial column-reduction of hidden @ (w + alpha*hebb).
// grid = (HS/4/256, ROW_CHUNKS), block = 256. Each thread owns 4 consecutive
// columns (float4) within one 32-row chunk; perfectly coalesced 16B/lane loads.
__global__ __launch_bounds__(256) void matvec_partial_k(
    const float* __restrict__ hidden, const float* __restrict__ w,
    const float* __restrict__ alpha, const float* __restrict__ hebb,
    float* __restrict__ partial) {
  const int j4 = blockIdx.x * blockDim.x + threadIdx.x;   // float4 column idx, 0..1023
  const int row0 = blockIdx.y * ROWS_PER_CHUNK;
  const size_t base = (size_t)row0 * (HS / 4) + j4;
  const float4* wp = reinterpret_cast<const float4*>(w) + base;
  const float4* ap = reinterpret_cast<const float4*>(alpha) + base;
  const float4* bp = reinterpret_cast<const float4*>(hebb) + base;
  float4 acc = make_float4(0.f, 0.f, 0.f, 0.f);
  for (int r = 0; r < ROWS_PER_CHUNK; ++r) {
    const float h = hidden[row0 + r];
    const float4 wv = wp[(size_t)r * (HS / 4)];
    const float4 av = ap[(size_t)r * (HS / 4)];
    const float4 bv = bp[(size_t)r * (HS / 4)];
    acc.x = fmaf(h, fmaf(av.x, bv.x, wv.x), acc.x);
    acc.y = fmaf(h, fmaf(av.y, bv.y, wv.y), acc.y);
    acc.z = fmaf(h, fmaf(av.z, bv.z, wv.z), acc.z);
    acc.w = fmaf(h, fmaf(av.w, bv.w, wv.w), acc.w);
  }
  reinterpret_cast<float4*>(partial)[(size_t)blockIdx.y * (HS / 4) + j4] = acc;
}

// Sum partials per column, add i2h(inputs)+bias, tanh -> hactiv (d_out+5).
__global__ __launch_bounds__(256) void finalize_k(
    const float* __restrict__ partial, const float* __restrict__ inputs,
    const float* __restrict__ i2h_w, const float* __restrict__ i2h_b,
    float* __restrict__ out_hactiv) {
  const int j = blockIdx.x * blockDim.x + threadIdx.x;
  float s = i2h_b[j];
#pragma unroll
  for (int k = 0; k < NIN; ++k) s = fmaf(inputs[k], i2h_w[j * NIN + k], s);
  float r = 0.f;
  for (int c = 0; c < ROW_CHUNKS; ++c) r += partial[c * HS + j];
  out_hactiv[j] = tanhf(s + r);
}

// 5 dot products: blocks 0..3 -> activout, block 4 -> valueout.
__global__ __launch_bounds__(256) void heads_k(
    const float* __restrict__ hactiv, const float* __restrict__ h2o_w,
    const float* __restrict__ h2o_b, const float* __restrict__ h2v_w,
    const float* __restrict__ h2v_b, float* __restrict__ out) {
  const int r = blockIdx.x;
  const float* wrow = (r < 4) ? (h2o_w + (size_t)r * HS) : h2v_w;
  float s = 0.f;
  for (int j = threadIdx.x; j < HS; j += 256) s = fmaf(hactiv[j], wrow[j], s);
  __shared__ float red[256];
  red[threadIdx.x] = s;
  __syncthreads();
  for (int off = 128; off > 0; off >>= 1) {
    if (threadIdx.x < off) red[threadIdx.x] += red[threadIdx.x + off];
    __syncthreads();
  }
  if (threadIdx.x == 0) {
    const float b = (r < 4) ? h2o_b[r] : h2v_b[0];
    out[r] = red[0] + b;   // out[0..3]=activout, out[4]=valueout
  }
}

// hebb_new = (1-eta)*hebb + eta*hidden[i]*hactiv[j].
// Output region starts at float-offset 4101 (4B-aligned only) -> scalar
// coalesced dword accesses; 65536 blocks keep BW near peak anyway.
__global__ __launch_bounds__(256) void hebb_update_k(
    const float* __restrict__ hebb, const float* __restrict__ hidden,
    const float* __restrict__ hactiv, const float* __restrict__ eta,
    float* __restrict__ out) {
  const int t = blockIdx.x * blockDim.x + threadIdx.x;
  const int i = t >> 12;          // row
  const int j = t & (HS - 1);     // col
  const float e = eta[0];
  out[t] = (1.f - e) * hebb[t] + e * hidden[i] * hactiv[j];
}

// Pass-through copy (dst only 4B-aligned -> scalar coalesced).
__global__ __launch_bounds__(256) void copy_k(
    const float* __restrict__ src, float* __restrict__ dst) {
  const int t = blockIdx.x * blockDim.x + threadIdx.x;
  dst[t] = src[t];
}

extern "C" void kernel_launch(void* const* d_in, const int* in_sizes, int n_in,
                              void* d_out, int out_size, void* d_ws, size_t ws_size,
                              hipStream_t stream) {
  const float* inputs = (const float*)d_in[0];
  const float* hidden = (const float*)d_in[1];
  const float* hebb   = (const float*)d_in[2];
  const float* et     = (const float*)d_in[3];
  const float* pw     = (const float*)d_in[4];
  const float* i2h_w  = (const float*)d_in[5];
  const float* i2h_b  = (const float*)d_in[6];
  const float* w      = (const float*)d_in[7];
  const float* alpha  = (const float*)d_in[8];
  const float* eta    = (const float*)d_in[9];
  const float* h2o_w  = (const float*)d_in[10];
  const float* h2o_b  = (const float*)d_in[11];
  const float* h2v_w  = (const float*)d_in[12];
  const float* h2v_b  = (const float*)d_in[13];

  float* out = (float*)d_out;
  const size_t NSQ = (size_t)HS * HS;
  // Output layout (flat, return order):
  float* out_heads  = out;               // activout[4] + valueout[1]
  float* out_hactiv = out + 5;           // [HS]
  float* out_hebb   = out + 5 + HS;      // [HS*HS]  (float offset 4101)
  float* out_et     = out_hebb + NSQ;
  float* out_pw     = out_et + NSQ;

  // Partial-sum scratch: 128*4096 floats = 2 MB. Prefer d_ws; if the workspace
  // is too small, stash in an aligned slice of the hebb output region (it is
  // fully consumed by finalize_k before hebb_update_k overwrites it).
  const size_t need = (size_t)ROW_CHUNKS * HS * sizeof(float);
  float* partial = (ws_size >= need) ? (float*)d_ws
                                     : (out_hebb + 3 /* -> float off 4104, 16B-aligned */);

  dim3 mv_grid(HS / 4 / 256, ROW_CHUNKS);           // (4, 128) = 512 blocks
  hipLaunchKernelGGL(matvec_partial_k, mv_grid, dim3(256), 0, stream,
                     hidden, w, alpha, hebb, partial);
  hipLaunchKernelGGL(finalize_k, dim3(HS / 256), dim3(256), 0, stream,
                     partial, inputs, i2h_w, i2h_b, out_hactiv);
  hipLaunchKernelGGL(heads_k, dim3(5), dim3(256), 0, stream,
                     out_hactiv, h2o_w, h2o_b, h2v_w, h2v_b, out_heads);
  hipLaunchKernelGGL(hebb_update_k, dim3((unsigned)(NSQ / 256)), dim3(256), 0, stream,
                     hebb, hidden, out_hactiv, eta, out_hebb);
  hipLaunchKernelGGL(copy_k, dim3((unsigned)(NSQ / 256)), dim3(256), 0, stream,
                     et, out_et);
  hipLaunchKernelGGL(copy_k, dim3((unsigned)(NSQ / 256)), dim3(256), 0, stream,
                     pw, out_pw);
}

// Round 2
// 488.536 us; speedup vs baseline: 1.0305x; 1.0305x over previous
//
#include <hip/hip_runtime.h>
#include <math.h>

#define HS 4096
#define NIN 17
#define ROW_CHUNKS 512
#define ROWS_PER_CHUNK (HS / ROW_CHUNKS)   // 8

// Partial column-reduction of hidden @ (w + alpha*hebb).
// grid = (4, 512), block = 256 -> 2048 blocks (8/CU, full latency hiding).
// Each thread: 8 fully-unrolled rows x 3 float4 loads = 24 loads in flight.
__global__ __launch_bounds__(256) void matvec_partial_k(
    const float* __restrict__ hidden, const float* __restrict__ w,
    const float* __restrict__ alpha, const float* __restrict__ hebb,
    float* __restrict__ partial) {
  const int j4 = blockIdx.x * blockDim.x + threadIdx.x;   // float4 col idx, 0..1023
  const int row0 = blockIdx.y * ROWS_PER_CHUNK;
  const size_t base = (size_t)row0 * (HS / 4) + j4;
  const float4* wp = reinterpret_cast<const float4*>(w) + base;
  const float4* ap = reinterpret_cast<const float4*>(alpha) + base;
  const float4* bp = reinterpret_cast<const float4*>(hebb) + base;
  float4 acc = make_float4(0.f, 0.f, 0.f, 0.f);
#pragma unroll
  for (int r = 0; r < ROWS_PER_CHUNK; ++r) {
    const float h = hidden[row0 + r];
    const float4 wv = wp[(size_t)r * (HS / 4)];
    const float4 av = ap[(size_t)r * (HS / 4)];
    const float4 bv = bp[(size_t)r * (HS / 4)];
    acc.x = fmaf(h, fmaf(av.x, bv.x, wv.x), acc.x);
    acc.y = fmaf(h, fmaf(av.y, bv.y, wv.y), acc.y);
    acc.z = fmaf(h, fmaf(av.z, bv.z, wv.z), acc.z);
    acc.w = fmaf(h, fmaf(av.w, bv.w, wv.w), acc.w);
  }
  reinterpret_cast<float4*>(partial)[(size_t)blockIdx.y * (HS / 4) + j4] = acc;
}

// Sum ROW_CHUNKS partials per column, add i2h(inputs)+bias, tanh -> hactiv.
__global__ __launch_bounds__(256) void finalize_k(
    const float* __restrict__ partial, const float* __restrict__ inputs,
    const float* __restrict__ i2h_w, const float* __restrict__ i2h_b,
    float* __restrict__ out_hactiv) {
  const int j = blockIdx.x * blockDim.x + threadIdx.x;
  float s = i2h_b[j];
#pragma unroll
  for (int k = 0; k < NIN; ++k) s = fmaf(inputs[k], i2h_w[j * NIN + k], s);
  float r = 0.f;
  for (int c = 0; c < ROW_CHUNKS; ++c) r += partial[(size_t)c * HS + j];
  out_hactiv[j] = tanhf(s + r);
}

// 5 dot products: blocks 0..3 -> activout, block 4 -> valueout.
__global__ __launch_bounds__(256) void heads_k(
    const float* __restrict__ hactiv, const float* __restrict__ h2o_w,
    const float* __restrict__ h2o_b, const float* __restrict__ h2v_w,
    const float* __restrict__ h2v_b, float* __restrict__ out) {
  const int r = blockIdx.x;
  const float* wrow = (r < 4) ? (h2o_w + (size_t)r * HS) : h2v_w;
  float s = 0.f;
  for (int j = threadIdx.x; j < HS; j += 256) s = fmaf(hactiv[j], wrow[j], s);
  __shared__ float red[256];
  red[threadIdx.x] = s;
  __syncthreads();
  for (int off = 128; off > 0; off >>= 1) {
    if (threadIdx.x < off) red[threadIdx.x] += red[threadIdx.x + off];
    __syncthreads();
  }
  if (threadIdx.x == 0) {
    const float b = (r < 4) ? h2o_b[r] : h2v_b[0];
    out[r] = red[0] + b;
  }
}

// Fused elementwise pass over 3 x HS*HS:
//   out_hebb = (1-eta)*hebb + eta*outer(hidden, hactiv); out_et = et; out_pw = pw.
// Grid-stride, wave-contiguous dword accesses (fill kernel proves 84% peak),
// ~32 elements per thread per loop -> dispatch overhead amortized.
__global__ __launch_bounds__(256) void elementwise_k(
    const float* __restrict__ hebb, const float* __restrict__ hidden,
    const float* __restrict__ hactiv, const float* __restrict__ eta,
    const float* __restrict__ et, const float* __restrict__ pw,
    float* __restrict__ out_hebb, float* __restrict__ out_et,
    float* __restrict__ out_pw) {
  const unsigned NSQ = (unsigned)HS * HS;           // 2^24
  const unsigned stride = gridDim.x * blockDim.x;
  const unsigned tid = blockIdx.x * blockDim.x + threadIdx.x;
  const float e = eta[0];
  const float one_m_e = 1.f - e;
  for (unsigned t = tid; t < NSQ; t += stride) {
    const float hi = hidden[t >> 12];
    const float ha = hactiv[t & (HS - 1)];
    out_hebb[t] = fmaf(one_m_e, hebb[t], e * hi * ha);
  }
  for (unsigned t = tid; t < NSQ; t += stride) out_et[t] = et[t];
  for (unsigned t = tid; t < NSQ; t += stride) out_pw[t] = pw[t];
}

extern "C" void kernel_launch(void* const* d_in, const int* in_sizes, int n_in,
                              void* d_out, int out_size, void* d_ws, size_t ws_size,
                              hipStream_t stream) {
  const float* inputs = (const float*)d_in[0];
  const float* hidden = (const float*)d_in[1];
  const float* hebb   = (const float*)d_in[2];
  const float* et     = (const float*)d_in[3];
  const float* pw     = (const float*)d_in[4];
  const float* i2h_w  = (const float*)d_in[5];
  const float* i2h_b  = (const float*)d_in[6];
  const float* w      = (const float*)d_in[7];
  const float* alpha  = (const float*)d_in[8];
  const float* eta    = (const float*)d_in[9];
  const float* h2o_w  = (const float*)d_in[10];
  const float* h2o_b  = (const float*)d_in[11];
  const float* h2v_w  = (const float*)d_in[12];
  const float* h2v_b  = (const float*)d_in[13];

  float* out = (float*)d_out;
  const size_t NSQ = (size_t)HS * HS;
  float* out_heads  = out;               // activout[4] + valueout[1]
  float* out_hactiv = out + 5;           // [HS]
  float* out_hebb   = out + 5 + HS;      // [HS*HS]  (float offset 4101)
  float* out_et     = out_hebb + NSQ;
  float* out_pw     = out_et + NSQ;

  // Partial scratch: 512*4096 floats = 8 MB. Prefer d_ws; else use an aligned
  // slice of the hebb output region (consumed by finalize_k before
  // elementwise_k overwrites it; stream order guarantees safety).
  const size_t need = (size_t)ROW_CHUNKS * HS * sizeof(float);
  float* partial = (ws_size >= need) ? (float*)d_ws
                                     : (out_hebb + 3 /* float off 4104, 16B-aligned */);

  hipLaunchKernelGGL(matvec_partial_k, dim3(HS / 4 / 256, ROW_CHUNKS), dim3(256),
                     0, stream, hidden, w, alpha, hebb, partial);
  hipLaunchKernelGGL(finalize_k, dim3(HS / 256), dim3(256), 0, stream,
                     partial, inputs, i2h_w, i2h_b, out_hactiv);
  hipLaunchKernelGGL(heads_k, dim3(5), dim3(256), 0, stream,
                     out_hactiv, h2o_w, h2o_b, h2v_w, h2v_b, out_heads);
  hipLaunchKernelGGL(elementwise_k, dim3(2048), dim3(256), 0, stream,
                     hebb, hidden, out_hactiv, eta, et, pw,
                     out_hebb, out_et, out_pw);
}

// Round 4
// 481.812 us; speedup vs baseline: 1.0449x; 1.0140x over previous
//
#include <hip/hip_runtime.h>
#include <math.h>

#define HS 4096
#define NIN 17
#define ROW_CHUNKS 512
#define ROWS_PER_CHUNK (HS / ROW_CHUNKS)   // 8

// Native vector type: __builtin_nontemporal_* accepts these (not HIP_vector_type).
typedef float vfloat4 __attribute__((ext_vector_type(4)));

__device__ __forceinline__ vfloat4 ntload4(const vfloat4* p) {
  return __builtin_nontemporal_load(p);
}
__device__ __forceinline__ float ntloadf(const float* p) {
  return __builtin_nontemporal_load(p);
}
__device__ __forceinline__ void ntstoref(float* p, float v) {
  __builtin_nontemporal_store(v, p);
}

// Kernel 1: matvec partials of hidden @ (w + alpha*hebb)  +  et/pw pass-through.
// grid (4, 512) x 256. Single-use streams (w, alpha, et, pw) use nt loads so
// hebb (reused by hebb_k) stays L3-resident.
__global__ __launch_bounds__(256) void matvec_copy_k(
    const float* __restrict__ hidden, const float* __restrict__ w,
    const float* __restrict__ alpha, const float* __restrict__ hebb,
    const float* __restrict__ et, const float* __restrict__ pw,
    float* __restrict__ partial, float* __restrict__ out_et,
    float* __restrict__ out_pw) {
  const int j4 = blockIdx.x * blockDim.x + threadIdx.x;   // float4 col idx, 0..1023
  const int row0 = blockIdx.y * ROWS_PER_CHUNK;
  const size_t base = (size_t)row0 * (HS / 4) + j4;
  const vfloat4* wp = reinterpret_cast<const vfloat4*>(w) + base;
  const vfloat4* ap = reinterpret_cast<const vfloat4*>(alpha) + base;
  const vfloat4* bp = reinterpret_cast<const vfloat4*>(hebb) + base;
  vfloat4 acc = (vfloat4)(0.f);
#pragma unroll
  for (int r = 0; r < ROWS_PER_CHUNK; ++r) {
    const float h = hidden[row0 + r];                    // block-uniform -> s_load
    const vfloat4 wv = ntload4(wp + (size_t)r * (HS / 4));
    const vfloat4 av = ntload4(ap + (size_t)r * (HS / 4));
    const vfloat4 bv = bp[(size_t)r * (HS / 4)];         // cached: reused by hebb_k
#pragma unroll
    for (int c = 0; c < 4; ++c)
      acc[c] = fmaf(h, fmaf(av[c], bv[c], wv[c]), acc[c]);
  }
  reinterpret_cast<vfloat4*>(partial)[(size_t)blockIdx.y * (HS / 4) + j4] = acc;

  // et/pw pass-through: 8192 floats per array per block, dword coalesced
  // (dst is only 4B-aligned). Overlaps with the matvec read burst.
  const size_t cbase = ((size_t)blockIdx.y * gridDim.x + blockIdx.x) * 8192 + threadIdx.x;
#pragma unroll
  for (int i = 0; i < 32; ++i) {
    const size_t t = cbase + (size_t)i * 256;
    ntstoref(out_et + t, ntloadf(et + t));
    ntstoref(out_pw + t, ntloadf(pw + t));
  }
}

// Kernel 2: one wave per column. Reduce 512 partials + i2h + bias, tanh.
__global__ __launch_bounds__(64) void finalize_k(
    const float* __restrict__ partial, const float* __restrict__ inputs,
    const float* __restrict__ i2h_w, const float* __restrict__ i2h_b,
    float* __restrict__ out_hactiv) {
  const int j = blockIdx.x;          // column
  const int lane = threadIdx.x;      // 0..63
  float s = 0.f;
#pragma unroll
  for (int i = 0; i < ROW_CHUNKS / 64; ++i)
    s += partial[(size_t)(lane + 64 * i) * HS + j];
  if (lane < NIN) s = fmaf(inputs[lane], i2h_w[j * NIN + lane], s);
#pragma unroll
  for (int off = 32; off > 0; off >>= 1) s += __shfl_down(s, off, 64);
  if (lane == 0) out_hactiv[j] = tanhf(s + i2h_b[j]);
}

// Kernel 3: 5 dot products (4 action head rows + value head).
__global__ __launch_bounds__(256) void heads_k(
    const float* __restrict__ hactiv, const float* __restrict__ h2o_w,
    const float* __restrict__ h2o_b, const float* __restrict__ h2v_w,
    const float* __restrict__ h2v_b, float* __restrict__ out) {
  const int r = blockIdx.x;
  const float* wrow = (r < 4) ? (h2o_w + (size_t)r * HS) : h2v_w;
  float s = 0.f;
  for (int j = threadIdx.x; j < HS; j += 256) s = fmaf(hactiv[j], wrow[j], s);
  __shared__ float red[256];
  red[threadIdx.x] = s;
  __syncthreads();
  for (int off = 128; off > 0; off >>= 1) {
    if (threadIdx.x < off) red[threadIdx.x] += red[threadIdx.x + off];
    __syncthreads();
  }
  if (threadIdx.x == 0) out[r] = red[0] + ((r < 4) ? h2o_b[r] : h2v_b[0]);
}

// Kernel 4: hebb_new = (1-eta)*hebb + eta*outer(hidden, hactiv).
// hebb read should be L3-warm from kernel 1 (nt streams avoided evicting it).
__global__ __launch_bounds__(256) void hebb_k(
    const float* __restrict__ hebb, const float* __restrict__ hidden,
    const float* __restrict__ hactiv, const float* __restrict__ eta,
    float* __restrict__ out_hebb) {
  const unsigned NSQ = (unsigned)HS * HS;
  const unsigned stride = gridDim.x * blockDim.x;
  const float e = eta[0];
  const float one_m_e = 1.f - e;
  for (unsigned t = blockIdx.x * blockDim.x + threadIdx.x; t < NSQ; t += stride) {
    const float hi = hidden[t >> 12];
    const float ha = hactiv[t & (HS - 1)];
    ntstoref(out_hebb + t, fmaf(one_m_e, hebb[t], e * hi * ha));
  }
}

extern "C" void kernel_launch(void* const* d_in, const int* in_sizes, int n_in,
                              void* d_out, int out_size, void* d_ws, size_t ws_size,
                              hipStream_t stream) {
  const float* inputs = (const float*)d_in[0];
  const float* hidden = (const float*)d_in[1];
  const float* hebb   = (const float*)d_in[2];
  const float* et     = (const float*)d_in[3];
  const float* pw     = (const float*)d_in[4];
  const float* i2h_w  = (const float*)d_in[5];
  const float* i2h_b  = (const float*)d_in[6];
  const float* w      = (const float*)d_in[7];
  const float* alpha  = (const float*)d_in[8];
  const float* eta    = (const float*)d_in[9];
  const float* h2o_w  = (const float*)d_in[10];
  const float* h2o_b  = (const float*)d_in[11];
  const float* h2v_w  = (const float*)d_in[12];
  const float* h2v_b  = (const float*)d_in[13];

  float* out = (float*)d_out;
  const size_t NSQ = (size_t)HS * HS;
  float* out_heads  = out;               // activout[4] + valueout[1]
  float* out_hactiv = out + 5;           // [HS]
  float* out_hebb   = out + 5 + HS;      // [HS*HS] (float offset 4101)
  float* out_et     = out_hebb + NSQ;
  float* out_pw     = out_et + NSQ;

  // Partial scratch: 512*4096 floats = 8 MB. Prefer d_ws; else an aligned
  // slice of the hebb output region (consumed before hebb_k overwrites it).
  const size_t need = (size_t)ROW_CHUNKS * HS * sizeof(float);
  float* partial = (ws_size >= need) ? (float*)d_ws
                                     : (out_hebb + 3 /* float off 4104, 16B-aligned */);

  hipLaunchKernelGGL(matvec_copy_k, dim3(HS / 4 / 256, ROW_CHUNKS), dim3(256),
                     0, stream, hidden, w, alpha, hebb, et, pw,
                     partial, out_et, out_pw);
  hipLaunchKernelGGL(finalize_k, dim3(HS), dim3(64), 0, stream,
                     partial, inputs, i2h_w, i2h_b, out_hactiv);
  hipLaunchKernelGGL(heads_k, dim3(5), dim3(256), 0, stream,
                     out_hactiv, h2o_w, h2o_b, h2v_w, h2v_b, out_heads);
  hipLaunchKernelGGL(hebb_k, dim3(2048), dim3(256), 0, stream,
                     hebb, hidden, out_hactiv, eta, out_hebb);
}